// Round 14
// baseline (277.454 us; speedup 1.0000x reference)
//
#include <hip/hip_runtime.h>

// Depth-4 path signature, N=64, L=512, C=8. Output/batch:
// [sig1(8) | sig2(64) | sig3(512) | sig4(4096)] = 4680 f32.
//
// R14 = R9 (proven 20.4us) + the register-neutral parts of R13 only:
//  * dx zero-padded to 4096 -> phase A len=32 constant, branch-free,
//    fully unrollable (compiler hoists ds_reads itself; R13's manual slot
//    pipeline spilled: VGPR capped 64, 320MB scratch fetch -> 240us).
//  * template<KQ>: dk0/dk1 compile-time component picks (-8 cndmask/step);
//    compile-time offsets in phases B/C and stores.
// Everything else byte-equivalent to R9: stage dx->LDS | A: wave w scans
// chunk w | slot lvl1-3 -> LDS (lvl3 stride 65) | B: exclusive prefix fold |
// C: contributions -> contrib[w] (no atomics) | reduce + stride-17 transpose
// -> coalesced lvl4 stores; wave15 writes lvl1-3 k-slice.

static constexpr int L = 512;
static constexpr int NC = 8;
static constexpr int NSEG = L - 1;                 // 511
static constexpr int SIG = 8 + 64 + 512 + 4096;    // 4680
static constexpr int DXF = 4096;                   // 511*8 zero-padded
static constexpr int SLOTOFF = DXF;                // 4096
static constexpr int SLOT = 592;                   // 8 + 64 + 520 (lvl3 stride 65)
static constexpr int CONTRIB = SLOTOFF + 16 * SLOT;  // 13568
static constexpr int TRANSO = CONTRIB + 16 * 1024;   // 29952
static constexpr int LDSF = TRANSO + 64 * 17 + 16;   // 31056 floats
static constexpr size_t LDS_BYTES = (size_t)LDSF * sizeof(float);  // ~121 KB

__device__ __forceinline__ float sel8(float d0, float d1, float d2, float d3,
                                      float d4, float d5, float d6, float d7,
                                      bool b0, bool b1, bool b2) {
    float x0 = b0 ? d1 : d0;
    float x1 = b0 ? d3 : d2;
    float x2 = b0 ? d5 : d4;
    float x3 = b0 ? d7 : d6;
    float y0 = b1 ? x1 : x0;
    float y1 = b1 ? x3 : x2;
    return b2 ? y1 : y0;
}

template <int KQ>
__device__ __forceinline__ void sig_body(float* lds, const float* __restrict__ path,
                                         float* __restrict__ out, const int tid,
                                         const int n) {
    const int w = tid >> 6;          // wave = chunk 0..15
    const int lane = tid & 63;       // (i,j)
    const int i = lane >> 3;
    const int j = lane & 7;

    // ---- stage dx into LDS (independent parallel loads) + zero pad ----
    {
        const float4* pv = reinterpret_cast<const float4*>(path + (size_t)n * (L * NC));
        if (tid < 1022) {
            const float4 a = pv[tid];
            const float4 b = pv[tid + 2];
            *reinterpret_cast<float4*>(&lds[tid * 4]) =
                make_float4(b.x - a.x, b.y - a.y, b.z - a.z, b.w - a.w);
        } else if (tid < 1024) {
            *reinterpret_cast<float4*>(&lds[tid * 4]) = make_float4(0.f, 0.f, 0.f, 0.f);
        }
    }
    __syncthreads();

    // ---------------- Phase A: branch-free chunk scan (LDS-fed) ----------
    const bool ib0 = lane & 8, ib1 = lane & 16, ib2 = lane & 32;
    const bool jb0 = lane & 1, jb1 = lane & 2, jb2 = lane & 4;

    float s1 = 0.f, s2 = 0.f, s3a = 0.f, s3b = 0.f;
    float s3[8];
    float accA[8], accB[8];
#pragma unroll
    for (int k = 0; k < 8; ++k) {
        s3[k] = 0.f;
        accA[k] = 0.f;
        accB[k] = 0.f;
    }
    constexpr float c3 = 1.f / 6.f;
    constexpr float c4 = 1.f / 24.f;

    const float* dbase = lds + (w * 32) * 8;
#pragma unroll
    for (int s = 0; s < 32; ++s) {
        const float4 A = *reinterpret_cast<const float4*>(dbase + s * 8);
        const float4 B = *reinterpret_cast<const float4*>(dbase + s * 8 + 4);
        const float d0 = A.x, d1 = A.y, d2 = A.z, d3 = A.w;
        const float d4 = B.x, d5 = B.y, d6 = B.z, d7 = B.w;

        const float di = sel8(d0, d1, d2, d3, d4, d5, d6, d7, ib0, ib1, ib2);
        const float dj = sel8(d0, d1, d2, d3, d4, d5, d6, d7, jb0, jb1, jb2);
        const float dk0 = (KQ == 0) ? d0 : (KQ == 1) ? d2 : (KQ == 2) ? d4 : d6;
        const float dk1 = (KQ == 0) ? d1 : (KQ == 1) ? d3 : (KQ == 2) ? d5 : d7;

        const float u = fmaf(s1, c3, di * c4);    // s1/6 + di/24
        float vv = fmaf(s1, dj * 0.5f, s2);       // s2 + s1*dj/2
        vv = fmaf(di * dj, c3, vv);               // + di*dj/6
        const float w_ = fmaf(s2, 0.5f, dj * u);  // s2/2 + dj*u

        const float Cc0 = fmaf(dk0, w_, s3a);     // uses OLD s3 slice
        const float Cc1 = fmaf(dk1, w_, s3b);

        accA[0] = fmaf(d0, Cc0, accA[0]);  accB[0] = fmaf(d0, Cc1, accB[0]);
        accA[1] = fmaf(d1, Cc0, accA[1]);  accB[1] = fmaf(d1, Cc1, accB[1]);
        accA[2] = fmaf(d2, Cc0, accA[2]);  accB[2] = fmaf(d2, Cc1, accB[2]);
        accA[3] = fmaf(d3, Cc0, accA[3]);  accB[3] = fmaf(d3, Cc1, accB[3]);
        accA[4] = fmaf(d4, Cc0, accA[4]);  accB[4] = fmaf(d4, Cc1, accB[4]);
        accA[5] = fmaf(d5, Cc0, accA[5]);  accB[5] = fmaf(d5, Cc1, accB[5]);
        accA[6] = fmaf(d6, Cc0, accA[6]);  accB[6] = fmaf(d6, Cc1, accB[6]);
        accA[7] = fmaf(d7, Cc0, accA[7]);  accB[7] = fmaf(d7, Cc1, accB[7]);
        s3[0] = fmaf(d0, vv, s3[0]);
        s3[1] = fmaf(d1, vv, s3[1]);
        s3[2] = fmaf(d2, vv, s3[2]);
        s3[3] = fmaf(d3, vv, s3[3]);
        s3[4] = fmaf(d4, vv, s3[4]);
        s3[5] = fmaf(d5, vv, s3[5]);
        s3[6] = fmaf(d6, vv, s3[6]);
        s3[7] = fmaf(d7, vv, s3[7]);

        s3a = fmaf(dk0, vv, s3a);
        s3b = fmaf(dk1, vv, s3b);
        s2 = fmaf(dj, fmaf(di, 0.5f, s1), s2);
        s1 += di;
    }

    // write chunk lvl1-3 to LDS slot w; lvl3 layout [t1*65 + t2*8 + t3]
    {
        float* sp = lds + SLOTOFF + w * SLOT;
        if (j == 0) sp[i] = s1;
        sp[8 + i * 8 + j] = s2;
        float* s3p = sp + 72 + i * 65 + j * 8;
#pragma unroll
        for (int k = 0; k < 8; ++k) s3p[k] = s3[k];
    }
    __syncthreads();

    // ---------------- Phase B: exclusive prefix fold (Chen, lvl1-3) ------
    float a1 = 0.f, a2 = 0.f, a3A = 0.f, a3B = 0.f;
    {
        const float* bp = lds + SLOTOFF;
        for (int b = 0; b < w; ++b, bp += SLOT) {
            const float b1i = bp[i], b1j = bp[j];
            const float b1k0 = bp[2 * KQ], b1k1 = bp[2 * KQ + 1];
            const float b2ij = bp[8 + i * 8 + j];
            const float b2jk0 = bp[8 + j * 8 + 2 * KQ];
            const float b2jk1 = bp[8 + j * 8 + 2 * KQ + 1];
            const float b3a = bp[72 + i * 65 + j * 8 + 2 * KQ];
            const float b3b = bp[72 + i * 65 + j * 8 + 2 * KQ + 1];
            a3A = fmaf(a2, b1k0, fmaf(a1, b2jk0, a3A + b3a));
            a3B = fmaf(a2, b1k1, fmaf(a1, b2jk1, a3B + b3b));
            a2 = fmaf(a1, b1j, a2 + b2ij);
            a1 += b1i;
        }
    }

    // ---------------- Phase C: contribution -> contrib[w][c*64+lane] -----
    {
        const float* cp = lds + SLOTOFF + w * SLOT;
        float* cb = lds + CONTRIB + w * 1024 + lane;
#pragma unroll
        for (int l = 0; l < 8; ++l) {
            const float b1l = cp[l];
            const float b2a = cp[8 + 16 * KQ + l];
            const float b2b = cp[8 + 16 * KQ + 8 + l];
            const float b3a = cp[72 + j * 65 + 16 * KQ + l];
            const float b3b = cp[72 + j * 65 + 16 * KQ + 8 + l];
            const float va = fmaf(a3A, b1l, fmaf(a2, b2a, fmaf(a1, b3a, accA[l])));
            const float vb = fmaf(a3B, b1l, fmaf(a2, b2b, fmaf(a1, b3b, accB[l])));
            cb[l * 64] = va;          // c = 0*8 + l
            cb[(8 + l) * 64] = vb;    // c = 1*8 + l
        }
    }

    // ---------------- final lvl1-3 (wave 15; lvl3 k-slice per block) -----
    if (w == 15) {
        const float* bp = lds + SLOTOFF + 15 * SLOT;
        const float b1i = bp[i], b1j = bp[j];
        const float b1k0 = bp[2 * KQ], b1k1 = bp[2 * KQ + 1];
        const float b2ij = bp[8 + i * 8 + j];
        const float b2jk0 = bp[8 + j * 8 + 2 * KQ];
        const float b2jk1 = bp[8 + j * 8 + 2 * KQ + 1];
        const float b3a = bp[72 + i * 65 + j * 8 + 2 * KQ];
        const float b3b = bp[72 + i * 65 + j * 8 + 2 * KQ + 1];
        a3A = fmaf(a2, b1k0, fmaf(a1, b2jk0, a3A + b3a));
        a3B = fmaf(a2, b1k1, fmaf(a1, b2jk1, a3B + b3b));
        a2 = fmaf(a1, b1j, a2 + b2ij);
        a1 += b1i;
        float* o = out + (size_t)n * SIG;
        o[72 + i * 64 + j * 8 + 2 * KQ] = a3A;
        o[72 + i * 64 + j * 8 + 2 * KQ + 1] = a3B;
        if (KQ == 0) {
            o[8 + i * 8 + j] = a2;
            if (j == 0) o[i] = a1;
        }
    }
    __syncthreads();

    // ---------------- reduce over w, transpose, coalesced store ----------
    {
        float s = 0.f;
        const float* c0 = lds + CONTRIB + tid;
#pragma unroll
        for (int ww = 0; ww < 16; ++ww) s += c0[ww * 1024];
        lds[TRANSO + (tid & 63) * 17 + (tid >> 6)] = s;
    }
    __syncthreads();
    if (tid < 256) {
        const int lp = tid >> 2, cq = tid & 3;
        const float* tp = lds + TRANSO + lp * 17 + cq * 4;
        float4 r;
        r.x = tp[0]; r.y = tp[1]; r.z = tp[2]; r.w = tp[3];
        *reinterpret_cast<float4*>(out + (size_t)n * SIG + 584 + lp * 64 + KQ * 16 + cq * 4) = r;
    }
}

__global__ __launch_bounds__(1024)
void sig_r14(const float* __restrict__ path, float* __restrict__ out) {
    extern __shared__ __align__(16) float lds[];
    const int tid = threadIdx.x;
    const int n = blockIdx.x >> 2;
    switch (blockIdx.x & 3) {
        case 0: sig_body<0>(lds, path, out, tid, n); break;
        case 1: sig_body<1>(lds, path, out, tid, n); break;
        case 2: sig_body<2>(lds, path, out, tid, n); break;
        default: sig_body<3>(lds, path, out, tid, n); break;
    }
}

extern "C" void kernel_launch(void* const* d_in, const int* in_sizes, int n_in,
                              void* d_out, int out_size, void* d_ws, size_t ws_size,
                              hipStream_t stream) {
    const float* path = (const float*)d_in[0];
    float* out = (float*)d_out;
    (void)hipFuncSetAttribute((const void*)sig_r14,
                              hipFuncAttributeMaxDynamicSharedMemorySize,
                              (int)LDS_BYTES);
    // 64 batches x 4 k-quarters = 256 blocks (1 per CU), 1024 threads each
    sig_r14<<<256, 1024, LDS_BYTES, stream>>>(path, out);
}

// Round 15
// 19.617 us; speedup vs baseline: 14.1439x; 14.1439x over previous
//
#include <hip/hip_runtime.h>

// Depth-4 path signature, N=64, L=512, C=8. Output/batch:
// [sig1(8) | sig2(64) | sig3(512) | sig4(4096)] = 4680 f32.
//
// R15 = R14 with spill fixes (R13/R14 lesson: 1024-thr blocks default to a
// 64-VGPR budget; FULL 32-step unroll blows it -> scratch catastrophe):
//  * #pragma unroll 4 (R9's proven pressure level), loop still branch-free
//    (dx zero-padded, constant trip count 32).
//  * amdgpu_waves_per_eu(4,4): 128-VGPR budget (R8-verified respected);
//    grid is 1 block/CU anyway.
// Keeps R14's wins: branch-free phase A, template<KQ> dk picks + compile-
// time offsets. Everything else identical to R9 (proven 20.4us).

static constexpr int L = 512;
static constexpr int NC = 8;
static constexpr int NSEG = L - 1;                 // 511
static constexpr int SIG = 8 + 64 + 512 + 4096;    // 4680
static constexpr int DXF = 4096;                   // 511*8 zero-padded
static constexpr int SLOTOFF = DXF;                // 4096
static constexpr int SLOT = 592;                   // 8 + 64 + 520 (lvl3 stride 65)
static constexpr int CONTRIB = SLOTOFF + 16 * SLOT;  // 13568
static constexpr int TRANSO = CONTRIB + 16 * 1024;   // 29952
static constexpr int LDSF = TRANSO + 64 * 17 + 16;   // 31056 floats
static constexpr size_t LDS_BYTES = (size_t)LDSF * sizeof(float);  // ~121 KB

__device__ __forceinline__ float sel8(float d0, float d1, float d2, float d3,
                                      float d4, float d5, float d6, float d7,
                                      bool b0, bool b1, bool b2) {
    float x0 = b0 ? d1 : d0;
    float x1 = b0 ? d3 : d2;
    float x2 = b0 ? d5 : d4;
    float x3 = b0 ? d7 : d6;
    float y0 = b1 ? x1 : x0;
    float y1 = b1 ? x3 : x2;
    return b2 ? y1 : y0;
}

template <int KQ>
__device__ __forceinline__ void sig_body(float* lds, const float* __restrict__ path,
                                         float* __restrict__ out, const int tid,
                                         const int n) {
    const int w = tid >> 6;          // wave = chunk 0..15
    const int lane = tid & 63;       // (i,j)
    const int i = lane >> 3;
    const int j = lane & 7;

    // ---- stage dx into LDS (independent parallel loads) + zero pad ----
    {
        const float4* pv = reinterpret_cast<const float4*>(path + (size_t)n * (L * NC));
        if (tid < 1022) {
            const float4 a = pv[tid];
            const float4 b = pv[tid + 2];
            *reinterpret_cast<float4*>(&lds[tid * 4]) =
                make_float4(b.x - a.x, b.y - a.y, b.z - a.z, b.w - a.w);
        } else if (tid < 1024) {
            *reinterpret_cast<float4*>(&lds[tid * 4]) = make_float4(0.f, 0.f, 0.f, 0.f);
        }
    }
    __syncthreads();

    // ---------------- Phase A: branch-free chunk scan (LDS-fed) ----------
    const bool ib0 = lane & 8, ib1 = lane & 16, ib2 = lane & 32;
    const bool jb0 = lane & 1, jb1 = lane & 2, jb2 = lane & 4;

    float s1 = 0.f, s2 = 0.f, s3a = 0.f, s3b = 0.f;
    float s3[8];
    float accA[8], accB[8];
#pragma unroll
    for (int k = 0; k < 8; ++k) {
        s3[k] = 0.f;
        accA[k] = 0.f;
        accB[k] = 0.f;
    }
    constexpr float c3 = 1.f / 6.f;
    constexpr float c4 = 1.f / 24.f;

    const float* dbase = lds + (w * 32) * 8;
#pragma unroll 4
    for (int s = 0; s < 32; ++s) {
        const float4 A = *reinterpret_cast<const float4*>(dbase + s * 8);
        const float4 B = *reinterpret_cast<const float4*>(dbase + s * 8 + 4);
        const float d0 = A.x, d1 = A.y, d2 = A.z, d3 = A.w;
        const float d4 = B.x, d5 = B.y, d6 = B.z, d7 = B.w;

        const float di = sel8(d0, d1, d2, d3, d4, d5, d6, d7, ib0, ib1, ib2);
        const float dj = sel8(d0, d1, d2, d3, d4, d5, d6, d7, jb0, jb1, jb2);
        const float dk0 = (KQ == 0) ? d0 : (KQ == 1) ? d2 : (KQ == 2) ? d4 : d6;
        const float dk1 = (KQ == 0) ? d1 : (KQ == 1) ? d3 : (KQ == 2) ? d5 : d7;

        const float u = fmaf(s1, c3, di * c4);    // s1/6 + di/24
        float vv = fmaf(s1, dj * 0.5f, s2);       // s2 + s1*dj/2
        vv = fmaf(di * dj, c3, vv);               // + di*dj/6
        const float w_ = fmaf(s2, 0.5f, dj * u);  // s2/2 + dj*u

        const float Cc0 = fmaf(dk0, w_, s3a);     // uses OLD s3 slice
        const float Cc1 = fmaf(dk1, w_, s3b);

        accA[0] = fmaf(d0, Cc0, accA[0]);  accB[0] = fmaf(d0, Cc1, accB[0]);
        accA[1] = fmaf(d1, Cc0, accA[1]);  accB[1] = fmaf(d1, Cc1, accB[1]);
        accA[2] = fmaf(d2, Cc0, accA[2]);  accB[2] = fmaf(d2, Cc1, accB[2]);
        accA[3] = fmaf(d3, Cc0, accA[3]);  accB[3] = fmaf(d3, Cc1, accB[3]);
        accA[4] = fmaf(d4, Cc0, accA[4]);  accB[4] = fmaf(d4, Cc1, accB[4]);
        accA[5] = fmaf(d5, Cc0, accA[5]);  accB[5] = fmaf(d5, Cc1, accB[5]);
        accA[6] = fmaf(d6, Cc0, accA[6]);  accB[6] = fmaf(d6, Cc1, accB[6]);
        accA[7] = fmaf(d7, Cc0, accA[7]);  accB[7] = fmaf(d7, Cc1, accB[7]);
        s3[0] = fmaf(d0, vv, s3[0]);
        s3[1] = fmaf(d1, vv, s3[1]);
        s3[2] = fmaf(d2, vv, s3[2]);
        s3[3] = fmaf(d3, vv, s3[3]);
        s3[4] = fmaf(d4, vv, s3[4]);
        s3[5] = fmaf(d5, vv, s3[5]);
        s3[6] = fmaf(d6, vv, s3[6]);
        s3[7] = fmaf(d7, vv, s3[7]);

        s3a = fmaf(dk0, vv, s3a);
        s3b = fmaf(dk1, vv, s3b);
        s2 = fmaf(dj, fmaf(di, 0.5f, s1), s2);
        s1 += di;
    }

    // write chunk lvl1-3 to LDS slot w; lvl3 layout [t1*65 + t2*8 + t3]
    {
        float* sp = lds + SLOTOFF + w * SLOT;
        if (j == 0) sp[i] = s1;
        sp[8 + i * 8 + j] = s2;
        float* s3p = sp + 72 + i * 65 + j * 8;
#pragma unroll
        for (int k = 0; k < 8; ++k) s3p[k] = s3[k];
    }
    __syncthreads();

    // ---------------- Phase B: exclusive prefix fold (Chen, lvl1-3) ------
    float a1 = 0.f, a2 = 0.f, a3A = 0.f, a3B = 0.f;
    {
        const float* bp = lds + SLOTOFF;
        for (int b = 0; b < w; ++b, bp += SLOT) {
            const float b1i = bp[i], b1j = bp[j];
            const float b1k0 = bp[2 * KQ], b1k1 = bp[2 * KQ + 1];
            const float b2ij = bp[8 + i * 8 + j];
            const float b2jk0 = bp[8 + j * 8 + 2 * KQ];
            const float b2jk1 = bp[8 + j * 8 + 2 * KQ + 1];
            const float b3a = bp[72 + i * 65 + j * 8 + 2 * KQ];
            const float b3b = bp[72 + i * 65 + j * 8 + 2 * KQ + 1];
            a3A = fmaf(a2, b1k0, fmaf(a1, b2jk0, a3A + b3a));
            a3B = fmaf(a2, b1k1, fmaf(a1, b2jk1, a3B + b3b));
            a2 = fmaf(a1, b1j, a2 + b2ij);
            a1 += b1i;
        }
    }

    // ---------------- Phase C: contribution -> contrib[w][c*64+lane] -----
    {
        const float* cp = lds + SLOTOFF + w * SLOT;
        float* cb = lds + CONTRIB + w * 1024 + lane;
#pragma unroll
        for (int l = 0; l < 8; ++l) {
            const float b1l = cp[l];
            const float b2a = cp[8 + 16 * KQ + l];
            const float b2b = cp[8 + 16 * KQ + 8 + l];
            const float b3a = cp[72 + j * 65 + 16 * KQ + l];
            const float b3b = cp[72 + j * 65 + 16 * KQ + 8 + l];
            const float va = fmaf(a3A, b1l, fmaf(a2, b2a, fmaf(a1, b3a, accA[l])));
            const float vb = fmaf(a3B, b1l, fmaf(a2, b2b, fmaf(a1, b3b, accB[l])));
            cb[l * 64] = va;          // c = 0*8 + l
            cb[(8 + l) * 64] = vb;    // c = 1*8 + l
        }
    }

    // ---------------- final lvl1-3 (wave 15; lvl3 k-slice per block) -----
    if (w == 15) {
        const float* bp = lds + SLOTOFF + 15 * SLOT;
        const float b1i = bp[i], b1j = bp[j];
        const float b1k0 = bp[2 * KQ], b1k1 = bp[2 * KQ + 1];
        const float b2ij = bp[8 + i * 8 + j];
        const float b2jk0 = bp[8 + j * 8 + 2 * KQ];
        const float b2jk1 = bp[8 + j * 8 + 2 * KQ + 1];
        const float b3a = bp[72 + i * 65 + j * 8 + 2 * KQ];
        const float b3b = bp[72 + i * 65 + j * 8 + 2 * KQ + 1];
        a3A = fmaf(a2, b1k0, fmaf(a1, b2jk0, a3A + b3a));
        a3B = fmaf(a2, b1k1, fmaf(a1, b2jk1, a3B + b3b));
        a2 = fmaf(a1, b1j, a2 + b2ij);
        a1 += b1i;
        float* o = out + (size_t)n * SIG;
        o[72 + i * 64 + j * 8 + 2 * KQ] = a3A;
        o[72 + i * 64 + j * 8 + 2 * KQ + 1] = a3B;
        if (KQ == 0) {
            o[8 + i * 8 + j] = a2;
            if (j == 0) o[i] = a1;
        }
    }
    __syncthreads();

    // ---------------- reduce over w, transpose, coalesced store ----------
    {
        float s = 0.f;
        const float* c0 = lds + CONTRIB + tid;
#pragma unroll
        for (int ww = 0; ww < 16; ++ww) s += c0[ww * 1024];
        lds[TRANSO + (tid & 63) * 17 + (tid >> 6)] = s;
    }
    __syncthreads();
    if (tid < 256) {
        const int lp = tid >> 2, cq = tid & 3;
        const float* tp = lds + TRANSO + lp * 17 + cq * 4;
        float4 r;
        r.x = tp[0]; r.y = tp[1]; r.z = tp[2]; r.w = tp[3];
        *reinterpret_cast<float4*>(out + (size_t)n * SIG + 584 + lp * 64 + KQ * 16 + cq * 4) = r;
    }
}

__global__ __launch_bounds__(1024)
__attribute__((amdgpu_waves_per_eu(4, 4)))
void sig_r15(const float* __restrict__ path, float* __restrict__ out) {
    extern __shared__ __align__(16) float lds[];
    const int tid = threadIdx.x;
    const int n = blockIdx.x >> 2;
    switch (blockIdx.x & 3) {
        case 0: sig_body<0>(lds, path, out, tid, n); break;
        case 1: sig_body<1>(lds, path, out, tid, n); break;
        case 2: sig_body<2>(lds, path, out, tid, n); break;
        default: sig_body<3>(lds, path, out, tid, n); break;
    }
}

extern "C" void kernel_launch(void* const* d_in, const int* in_sizes, int n_in,
                              void* d_out, int out_size, void* d_ws, size_t ws_size,
                              hipStream_t stream) {
    const float* path = (const float*)d_in[0];
    float* out = (float*)d_out;
    (void)hipFuncSetAttribute((const void*)sig_r15,
                              hipFuncAttributeMaxDynamicSharedMemorySize,
                              (int)LDS_BYTES);
    // 64 batches x 4 k-quarters = 256 blocks (1 per CU), 1024 threads each
    sig_r15<<<256, 1024, LDS_BYTES, stream>>>(path, out);
}

// Round 16
// 16.985 us; speedup vs baseline: 16.3355x; 1.1550x over previous
//
#include <hip/hip_runtime.h>

// Depth-4 path signature, N=64, L=512, C=8. Output/batch:
// [sig1(8) | sig2(64) | sig3(512) | sig4(4096)] = 4680 f32.
//
// R16 = R15 (19.6us) with ONE isolated change: di/dj come from per-lane
// broadcast ds_read_b32 (lane(i,j) reads dbase+s*8+i / +j; 8 consecutive
// addresses -> 8 banks, 8-lane broadcast, conflict-free; imm offsets under
// unroll-4) instead of two 7-cndmask sel8 trees. -14 VALU/step on phase A
// (the measured ~9us majority phase), +2 cheap LDS ops/step.
// Spill discipline (R13/R14 lesson) kept: #pragma unroll 4 +
// amdgpu_waves_per_eu(4,4) (128-VGPR budget; grid is 1 block/CU anyway).

static constexpr int L = 512;
static constexpr int NC = 8;
static constexpr int NSEG = L - 1;                 // 511
static constexpr int SIG = 8 + 64 + 512 + 4096;    // 4680
static constexpr int DXF = 4096;                   // 511*8 zero-padded
static constexpr int SLOTOFF = DXF;                // 4096
static constexpr int SLOT = 592;                   // 8 + 64 + 520 (lvl3 stride 65)
static constexpr int CONTRIB = SLOTOFF + 16 * SLOT;  // 13568
static constexpr int TRANSO = CONTRIB + 16 * 1024;   // 29952
static constexpr int LDSF = TRANSO + 64 * 17 + 16;   // 31056 floats
static constexpr size_t LDS_BYTES = (size_t)LDSF * sizeof(float);  // ~121 KB

template <int KQ>
__device__ __forceinline__ void sig_body(float* lds, const float* __restrict__ path,
                                         float* __restrict__ out, const int tid,
                                         const int n) {
    const int w = tid >> 6;          // wave = chunk 0..15
    const int lane = tid & 63;       // (i,j)
    const int i = lane >> 3;
    const int j = lane & 7;

    // ---- stage dx into LDS (independent parallel loads) + zero pad ----
    {
        const float4* pv = reinterpret_cast<const float4*>(path + (size_t)n * (L * NC));
        if (tid < 1022) {
            const float4 a = pv[tid];
            const float4 b = pv[tid + 2];
            *reinterpret_cast<float4*>(&lds[tid * 4]) =
                make_float4(b.x - a.x, b.y - a.y, b.z - a.z, b.w - a.w);
        } else if (tid < 1024) {
            *reinterpret_cast<float4*>(&lds[tid * 4]) = make_float4(0.f, 0.f, 0.f, 0.f);
        }
    }
    __syncthreads();

    // ---------------- Phase A: branch-free chunk scan (LDS-fed) ----------
    float s1 = 0.f, s2 = 0.f, s3a = 0.f, s3b = 0.f;
    float s3[8];
    float accA[8], accB[8];
#pragma unroll
    for (int k = 0; k < 8; ++k) {
        s3[k] = 0.f;
        accA[k] = 0.f;
        accB[k] = 0.f;
    }
    constexpr float c3 = 1.f / 6.f;
    constexpr float c4 = 1.f / 24.f;

    const float* dbase = lds + (w * 32) * 8;
    const float* bI = dbase + i;   // per-lane di base: 8 addrs, 8 banks, broadcast
    const float* bJ = dbase + j;   // per-lane dj base
#pragma unroll 4
    for (int s = 0; s < 32; ++s) {
        const float4 A = *reinterpret_cast<const float4*>(dbase + s * 8);
        const float4 B = *reinterpret_cast<const float4*>(dbase + s * 8 + 4);
        const float di = bI[s * 8];
        const float dj = bJ[s * 8];
        const float d0 = A.x, d1 = A.y, d2 = A.z, d3 = A.w;
        const float d4 = B.x, d5 = B.y, d6 = B.z, d7 = B.w;
        const float dk0 = (KQ == 0) ? d0 : (KQ == 1) ? d2 : (KQ == 2) ? d4 : d6;
        const float dk1 = (KQ == 0) ? d1 : (KQ == 1) ? d3 : (KQ == 2) ? d5 : d7;

        const float u = fmaf(s1, c3, di * c4);    // s1/6 + di/24
        float vv = fmaf(s1, dj * 0.5f, s2);       // s2 + s1*dj/2
        vv = fmaf(di * dj, c3, vv);               // + di*dj/6
        const float w_ = fmaf(s2, 0.5f, dj * u);  // s2/2 + dj*u

        const float Cc0 = fmaf(dk0, w_, s3a);     // uses OLD s3 slice
        const float Cc1 = fmaf(dk1, w_, s3b);

        accA[0] = fmaf(d0, Cc0, accA[0]);  accB[0] = fmaf(d0, Cc1, accB[0]);
        accA[1] = fmaf(d1, Cc0, accA[1]);  accB[1] = fmaf(d1, Cc1, accB[1]);
        accA[2] = fmaf(d2, Cc0, accA[2]);  accB[2] = fmaf(d2, Cc1, accB[2]);
        accA[3] = fmaf(d3, Cc0, accA[3]);  accB[3] = fmaf(d3, Cc1, accB[3]);
        accA[4] = fmaf(d4, Cc0, accA[4]);  accB[4] = fmaf(d4, Cc1, accB[4]);
        accA[5] = fmaf(d5, Cc0, accA[5]);  accB[5] = fmaf(d5, Cc1, accB[5]);
        accA[6] = fmaf(d6, Cc0, accA[6]);  accB[6] = fmaf(d6, Cc1, accB[6]);
        accA[7] = fmaf(d7, Cc0, accA[7]);  accB[7] = fmaf(d7, Cc1, accB[7]);
        s3[0] = fmaf(d0, vv, s3[0]);
        s3[1] = fmaf(d1, vv, s3[1]);
        s3[2] = fmaf(d2, vv, s3[2]);
        s3[3] = fmaf(d3, vv, s3[3]);
        s3[4] = fmaf(d4, vv, s3[4]);
        s3[5] = fmaf(d5, vv, s3[5]);
        s3[6] = fmaf(d6, vv, s3[6]);
        s3[7] = fmaf(d7, vv, s3[7]);

        s3a = fmaf(dk0, vv, s3a);
        s3b = fmaf(dk1, vv, s3b);
        s2 = fmaf(dj, fmaf(di, 0.5f, s1), s2);
        s1 += di;
    }

    // write chunk lvl1-3 to LDS slot w; lvl3 layout [t1*65 + t2*8 + t3]
    {
        float* sp = lds + SLOTOFF + w * SLOT;
        if (j == 0) sp[i] = s1;
        sp[8 + i * 8 + j] = s2;
        float* s3p = sp + 72 + i * 65 + j * 8;
#pragma unroll
        for (int k = 0; k < 8; ++k) s3p[k] = s3[k];
    }
    __syncthreads();

    // ---------------- Phase B: exclusive prefix fold (Chen, lvl1-3) ------
    float a1 = 0.f, a2 = 0.f, a3A = 0.f, a3B = 0.f;
    {
        const float* bp = lds + SLOTOFF;
        for (int b = 0; b < w; ++b, bp += SLOT) {
            const float b1i = bp[i], b1j = bp[j];
            const float b1k0 = bp[2 * KQ], b1k1 = bp[2 * KQ + 1];
            const float b2ij = bp[8 + i * 8 + j];
            const float b2jk0 = bp[8 + j * 8 + 2 * KQ];
            const float b2jk1 = bp[8 + j * 8 + 2 * KQ + 1];
            const float b3a = bp[72 + i * 65 + j * 8 + 2 * KQ];
            const float b3b = bp[72 + i * 65 + j * 8 + 2 * KQ + 1];
            a3A = fmaf(a2, b1k0, fmaf(a1, b2jk0, a3A + b3a));
            a3B = fmaf(a2, b1k1, fmaf(a1, b2jk1, a3B + b3b));
            a2 = fmaf(a1, b1j, a2 + b2ij);
            a1 += b1i;
        }
    }

    // ---------------- Phase C: contribution -> contrib[w][c*64+lane] -----
    {
        const float* cp = lds + SLOTOFF + w * SLOT;
        float* cb = lds + CONTRIB + w * 1024 + lane;
#pragma unroll
        for (int l = 0; l < 8; ++l) {
            const float b1l = cp[l];
            const float b2a = cp[8 + 16 * KQ + l];
            const float b2b = cp[8 + 16 * KQ + 8 + l];
            const float b3a = cp[72 + j * 65 + 16 * KQ + l];
            const float b3b = cp[72 + j * 65 + 16 * KQ + 8 + l];
            const float va = fmaf(a3A, b1l, fmaf(a2, b2a, fmaf(a1, b3a, accA[l])));
            const float vb = fmaf(a3B, b1l, fmaf(a2, b2b, fmaf(a1, b3b, accB[l])));
            cb[l * 64] = va;          // c = 0*8 + l
            cb[(8 + l) * 64] = vb;    // c = 1*8 + l
        }
    }

    // ---------------- final lvl1-3 (wave 15; lvl3 k-slice per block) -----
    if (w == 15) {
        const float* bp = lds + SLOTOFF + 15 * SLOT;
        const float b1i = bp[i], b1j = bp[j];
        const float b1k0 = bp[2 * KQ], b1k1 = bp[2 * KQ + 1];
        const float b2ij = bp[8 + i * 8 + j];
        const float b2jk0 = bp[8 + j * 8 + 2 * KQ];
        const float b2jk1 = bp[8 + j * 8 + 2 * KQ + 1];
        const float b3a = bp[72 + i * 65 + j * 8 + 2 * KQ];
        const float b3b = bp[72 + i * 65 + j * 8 + 2 * KQ + 1];
        a3A = fmaf(a2, b1k0, fmaf(a1, b2jk0, a3A + b3a));
        a3B = fmaf(a2, b1k1, fmaf(a1, b2jk1, a3B + b3b));
        a2 = fmaf(a1, b1j, a2 + b2ij);
        a1 += b1i;
        float* o = out + (size_t)n * SIG;
        o[72 + i * 64 + j * 8 + 2 * KQ] = a3A;
        o[72 + i * 64 + j * 8 + 2 * KQ + 1] = a3B;
        if (KQ == 0) {
            o[8 + i * 8 + j] = a2;
            if (j == 0) o[i] = a1;
        }
    }
    __syncthreads();

    // ---------------- reduce over w, transpose, coalesced store ----------
    {
        float s = 0.f;
        const float* c0 = lds + CONTRIB + tid;
#pragma unroll
        for (int ww = 0; ww < 16; ++ww) s += c0[ww * 1024];
        lds[TRANSO + (tid & 63) * 17 + (tid >> 6)] = s;
    }
    __syncthreads();
    if (tid < 256) {
        const int lp = tid >> 2, cq = tid & 3;
        const float* tp = lds + TRANSO + lp * 17 + cq * 4;
        float4 r;
        r.x = tp[0]; r.y = tp[1]; r.z = tp[2]; r.w = tp[3];
        *reinterpret_cast<float4*>(out + (size_t)n * SIG + 584 + lp * 64 + KQ * 16 + cq * 4) = r;
    }
}

__global__ __launch_bounds__(1024)
__attribute__((amdgpu_waves_per_eu(4, 4)))
void sig_r16(const float* __restrict__ path, float* __restrict__ out) {
    extern __shared__ __align__(16) float lds[];
    const int tid = threadIdx.x;
    const int n = blockIdx.x >> 2;
    switch (blockIdx.x & 3) {
        case 0: sig_body<0>(lds, path, out, tid, n); break;
        case 1: sig_body<1>(lds, path, out, tid, n); break;
        case 2: sig_body<2>(lds, path, out, tid, n); break;
        default: sig_body<3>(lds, path, out, tid, n); break;
    }
}

extern "C" void kernel_launch(void* const* d_in, const int* in_sizes, int n_in,
                              void* d_out, int out_size, void* d_ws, size_t ws_size,
                              hipStream_t stream) {
    const float* path = (const float*)d_in[0];
    float* out = (float*)d_out;
    (void)hipFuncSetAttribute((const void*)sig_r16,
                              hipFuncAttributeMaxDynamicSharedMemorySize,
                              (int)LDS_BYTES);
    // 64 batches x 4 k-quarters = 256 blocks (1 per CU), 1024 threads each
    sig_r16<<<256, 1024, LDS_BYTES, stream>>>(path, out);
}